// Round 1
// baseline (695.641 us; speedup 1.0000x reference)
//
#include <hip/hip_runtime.h>

#define S_LEN 2048
#define DIM   4096
#define NH    32
#define NKV   8
#define HD    128

typedef unsigned short u16;
typedef __bf16 bf16x8 __attribute__((ext_vector_type(8)));
typedef float  f32x4  __attribute__((ext_vector_type(4)));

__device__ __forceinline__ u16 f2bf(float f) {
  unsigned u = __float_as_uint(f);
  u += 0x7FFFu + ((u >> 16) & 1u);   // RNE
  return (u16)(u >> 16);
}
__device__ __forceinline__ float bf2f(u16 v) {
  return __uint_as_float(((unsigned)v) << 16);
}
__device__ __forceinline__ void async16(void* lds, const void* g) {
  __builtin_amdgcn_global_load_lds((const __attribute__((address_space(1))) void*)g,
                                   (__attribute__((address_space(3))) void*)lds,
                                   16, 0, 0);
}

// ---------------- f32 -> bf16 convert (vectorized) ----------------
__global__ void conv_bf16(const float* __restrict__ in, u16* __restrict__ out, int n4) {
  int stride = gridDim.x * blockDim.x;
  for (int i = blockIdx.x * blockDim.x + threadIdx.x; i < n4; i += stride) {
    float4 v = ((const float4*)in)[i];
    ushort4 o = make_ushort4(f2bf(v.x), f2bf(v.y), f2bf(v.z), f2bf(v.w));
    ((ushort4*)out)[i] = o;
  }
}

// ---------------- RoPE cos/sin table ----------------
__global__ void rope_table(float* __restrict__ cs, float* __restrict__ sn) {
  int idx = blockIdx.x * blockDim.x + threadIdx.x;   // S_LEN*64
  if (idx >= S_LEN * 64) return;
  int i = idx & 63, t = idx >> 6;
  float freq = powf(500000.0f, -(float)(2 * i) / 128.0f);
  float ang = (float)t * freq;
  cs[idx] = cosf(ang);
  sn[idx] = sinf(ang);
}

// ---------------- RoPE in-place on bf16 (seq, nheads*HD) ----------------
__global__ void rope_apply(u16* __restrict__ T, const float* __restrict__ cs,
                           const float* __restrict__ sn, int nheads, int total) {
  int idx = blockIdx.x * blockDim.x + threadIdx.x;
  if (idx >= total) return;
  int i = idx & 63;
  int tmp = idx >> 6;
  int hh = tmp % nheads;
  int t  = tmp / nheads;
  u16* p = T + (size_t)t * (nheads * HD) + hh * HD + 2 * i;
  float c = cs[t * 64 + i], s = sn[t * 64 + i];
  float te = bf2f(p[0]), to = bf2f(p[1]);
  p[0] = f2bf(te * c - to * s);
  p[1] = f2bf(te * s + to * c);
}

// ---------------- bf16 GEMM: C[m,n] = sum_k A[m,k]*B[n,k] ----------------
// m97-structure: 128x128 tile, BK=32, 4 waves (2x2), 4x4 16x16x32 frags/wave.
template<int OUT_BF16>
__global__ __launch_bounds__(256) void gemm_bt(const u16* __restrict__ A,
                                               const u16* __restrict__ B,
                                               void* __restrict__ Cout,
                                               int M, int N, int K) {
  __shared__ alignas(16) u16 As[128 * 32];
  __shared__ alignas(16) u16 Bs[128 * 32];
  const int tid = threadIdx.x;
  const int w = tid >> 6, l = tid & 63;
  const int lrow = l & 15, lk = l >> 4;
  const int m0 = blockIdx.y * 128, n0 = blockIdx.x * 128;
  const int wr = w >> 1, wc = w & 1;
  f32x4 acc[4][4] = {};
  const int srow  = tid >> 2;          // staging row 0..63
  const int scolb = (tid & 3) * 16;    // byte col within 64B row
  const char* Ab = (const char*)A;
  const char* Bb = (const char*)B;
  char* AsB = (char*)As + (size_t)w * 1024;
  char* BsB = (char*)Bs + (size_t)w * 1024;
  const size_t rowskip = (size_t)64 * K * 2;
  for (int k0 = 0; k0 < K; k0 += 32) {
    const char* ga = Ab + ((size_t)(m0 + srow) * K + k0) * 2 + scolb;
    const char* gb = Bb + ((size_t)(n0 + srow) * K + k0) * 2 + scolb;
    async16(AsB,        ga);
    async16(AsB + 4096, ga + rowskip);
    async16(BsB,        gb);
    async16(BsB + 4096, gb + rowskip);
    __syncthreads();
    bf16x8 af[4], bfr[4];
#pragma unroll
    for (int i = 0; i < 4; ++i)
      af[i] = *(const bf16x8*)&As[(wr * 64 + i * 16 + lrow) * 32 + lk * 8];
#pragma unroll
    for (int i = 0; i < 4; ++i)
      bfr[i] = *(const bf16x8*)&Bs[(wc * 64 + i * 16 + lrow) * 32 + lk * 8];
#pragma unroll
    for (int mi = 0; mi < 4; ++mi)
#pragma unroll
      for (int ni = 0; ni < 4; ++ni)
        acc[mi][ni] = __builtin_amdgcn_mfma_f32_16x16x32_bf16(af[mi], bfr[ni], acc[mi][ni], 0, 0, 0);
    __syncthreads();
  }
  // C/D layout (m89-verified): col = lane&15, row = (lane>>4)*4 + j
  if (OUT_BF16) {
    u16* C = (u16*)Cout;
#pragma unroll
    for (int mi = 0; mi < 4; ++mi)
#pragma unroll
      for (int ni = 0; ni < 4; ++ni) {
        int row = m0 + wr * 64 + mi * 16 + lk * 4;
        int col = n0 + wc * 64 + ni * 16 + lrow;
#pragma unroll
        for (int j = 0; j < 4; ++j)
          C[(size_t)(row + j) * N + col] = f2bf(acc[mi][ni][j]);
      }
  } else {
    float* C = (float*)Cout;
#pragma unroll
    for (int mi = 0; mi < 4; ++mi)
#pragma unroll
      for (int ni = 0; ni < 4; ++ni) {
        int row = m0 + wr * 64 + mi * 16 + lk * 4;
        int col = n0 + wc * 64 + ni * 16 + lrow;
#pragma unroll
        for (int j = 0; j < 4; ++j)
          C[(size_t)(row + j) * N + col] = acc[mi][ni][j];
      }
  }
}

// ---------------- flash attention, causal, GQA 32/8 ----------------
// grid (S/64, NH), 256 threads. Per wave: 16 q-rows. 32-key tiles.
__global__ __launch_bounds__(256) void attn_fwd(const u16* __restrict__ Q,
                                                const u16* __restrict__ Km,
                                                const u16* __restrict__ Vm,
                                                u16* __restrict__ O) {
  __shared__ alignas(16) u16 Ks[32 * 128];      // XOR-swizzled rows
  __shared__ alignas(16) u16 VTs[128 * 32];     // V transposed [d][k]
  __shared__ alignas(16) u16 Ps[4][16 * 32];    // per-wave P tile
  const int tid = threadIdx.x;
  const int w = tid >> 6, l = tid & 63;
  const int lrow = l & 15, lk = l >> 4;
  const int h  = blockIdx.y;
  const int q0 = blockIdx.x * 64;
  const int hk = h >> 2;
  const float scale = 0.08838834764831845f;   // 1/sqrt(128)

  // Q fragments in registers: row = q0 + w*16 + lrow
  bf16x8 qf[4];
  {
    const u16* qp = Q + (size_t)(q0 + w * 16 + lrow) * DIM + h * HD;
#pragma unroll
    for (int kk = 0; kk < 4; ++kk)
      qf[kk] = *(const bf16x8*)&qp[kk * 32 + lk * 8];
  }
  float m_r[4], s_r[4];
#pragma unroll
  for (int j = 0; j < 4; ++j) { m_r[j] = -1e30f; s_r[j] = 0.f; }
  f32x4 o_acc[8] = {};

  const int krow0 = w * 4 + lk;          // K staging row (issue 0)
  const int kcbs  = lrow * 16;           // swizzled byte col (linear LDS slot)
  const int vr  = l & 31;                // V staging row
  const int vc0h = (tid >> 5) * 8;       // V col base, +64 on 2nd iter

  const int ntiles = q0 / 32 + 2;
  for (int t = 0; t < ntiles; ++t) {
    const int j0 = t * 32;
    // --- stage K (global_load_lds, source pre-swizzled: byte ^= (row&7)<<4) ---
#pragma unroll
    for (int i = 0; i < 2; ++i) {
      int row = i * 16 + krow0;
      int cb = kcbs ^ ((row & 7) << 4);
      const char* gk = (const char*)Km + ((size_t)(j0 + row) * (NKV * HD) + hk * HD) * 2 + cb;
      async16((char*)Ks + i * 4096 + (size_t)w * 1024, gk);
    }
    // --- stage V transposed via regs ---
#pragma unroll
    for (int it = 0; it < 2; ++it) {
      int c0 = vc0h + it * 64;
      const u16* vp = Vm + (size_t)(j0 + vr) * (NKV * HD) + hk * HD + c0;
      uint4 raw = *(const uint4*)vp;
      const u16* pe = (const u16*)&raw;
#pragma unroll
      for (int e = 0; e < 8; ++e)
        VTs[(c0 + e) * 32 + vr] = pe[e];
    }
    __syncthreads();

    // --- QK^T: S[q=lk*4+j][key=ni*16+lrow] ---
    f32x4 sc[2] = {};
#pragma unroll
    for (int ni = 0; ni < 2; ++ni)
#pragma unroll
      for (int kk = 0; kk < 4; ++kk) {
        int krow = ni * 16 + lrow;
        int cb = (kk * 64 + lk * 16) ^ ((krow & 7) << 4);
        bf16x8 kf = *(const bf16x8*)((const char*)Ks + krow * 256 + cb);
        sc[ni] = __builtin_amdgcn_mfma_f32_16x16x32_bf16(qf[kk], kf, sc[ni], 0, 0, 0);
      }
    // --- scale + causal mask ---
    const int qrb = q0 + w * 16 + lk * 4;
    float tm[4];
#pragma unroll
    for (int j = 0; j < 4; ++j) tm[j] = -1e30f;
#pragma unroll
    for (int ni = 0; ni < 2; ++ni)
#pragma unroll
      for (int j = 0; j < 4; ++j) {
        int kg = j0 + ni * 16 + lrow;
        float sv = sc[ni][j] * scale;
        sv = (kg <= qrb + j) ? sv : -1e30f;
        sc[ni][j] = sv;
        tm[j] = fmaxf(tm[j], sv);
      }
    // --- row max across the 16 lanes of the group ---
#pragma unroll
    for (int mask = 1; mask < 16; mask <<= 1)
#pragma unroll
      for (int j = 0; j < 4; ++j) tm[j] = fmaxf(tm[j], __shfl_xor(tm[j], mask));
    float corr[4], rs[4];
#pragma unroll
    for (int j = 0; j < 4; ++j) {
      float mn = fmaxf(m_r[j], tm[j]);
      corr[j] = __expf(m_r[j] - mn);
      m_r[j] = mn;
      rs[j] = 0.f;
    }
#pragma unroll
    for (int ni = 0; ni < 2; ++ni)
#pragma unroll
      for (int j = 0; j < 4; ++j) {
        float p = __expf(sc[ni][j] - m_r[j]);
        sc[ni][j] = p;
        rs[j] += p;
      }
#pragma unroll
    for (int mask = 1; mask < 16; mask <<= 1)
#pragma unroll
      for (int j = 0; j < 4; ++j) rs[j] += __shfl_xor(rs[j], mask);
#pragma unroll
    for (int j = 0; j < 4; ++j) s_r[j] = s_r[j] * corr[j] + rs[j];
    // --- rescale O ---
#pragma unroll
    for (int dn = 0; dn < 8; ++dn)
#pragma unroll
      for (int j = 0; j < 4; ++j) o_acc[dn][j] *= corr[j];
    // --- P -> per-wave LDS (bf16), then PV ---
#pragma unroll
    for (int ni = 0; ni < 2; ++ni)
#pragma unroll
      for (int j = 0; j < 4; ++j)
        Ps[w][(lk * 4 + j) * 32 + ni * 16 + lrow] = f2bf(sc[ni][j]);
    __asm__ volatile("s_waitcnt lgkmcnt(0)" ::: "memory");
    bf16x8 pf = *(const bf16x8*)&Ps[w][lrow * 32 + lk * 8];
#pragma unroll
    for (int dn = 0; dn < 8; ++dn) {
      bf16x8 vf = *(const bf16x8*)&VTs[(dn * 16 + lrow) * 32 + lk * 8];
      o_acc[dn] = __builtin_amdgcn_mfma_f32_16x16x32_bf16(pf, vf, o_acc[dn], 0, 0, 0);
    }
    __syncthreads();
  }
  // --- normalize + write ---
  float inv[4];
#pragma unroll
  for (int j = 0; j < 4; ++j) inv[j] = 1.0f / s_r[j];
  u16* op = O + (size_t)(q0 + w * 16 + lk * 4) * DIM + h * HD;
#pragma unroll
  for (int dn = 0; dn < 8; ++dn)
#pragma unroll
    for (int j = 0; j < 4; ++j)
      op[(size_t)j * DIM + dn * 16 + lrow] = f2bf(o_acc[dn][j] * inv[j]);
}

// ---------------- host launcher ----------------
extern "C" void kernel_launch(void* const* d_in, const int* in_sizes, int n_in,
                              void* d_out, int out_size, void* d_ws, size_t ws_size,
                              hipStream_t stream) {
  (void)in_sizes; (void)n_in; (void)out_size;
  const float* x  = (const float*)d_in[0];
  const float* wq = (const float*)d_in[2];
  const float* wk = (const float*)d_in[3];
  const float* wv = (const float*)d_in[4];
  const float* wo = (const float*)d_in[5];

  char* ws = (char*)d_ws;
  u16*   xb   = (u16*)(ws + 0);                       // 16 MB
  u16*   wqb  = (u16*)(ws + 16777216ull);             // 32 MB
  u16*   wkb  = (u16*)(ws + 50331648ull);             // 8 MB
  u16*   wvb  = (u16*)(ws + 58720256ull);             // 8 MB
  u16*   wob  = (u16*)(ws + 67108864ull);             // 32 MB
  u16*   Qb   = (u16*)(ws + 100663296ull);            // 16 MB
  u16*   Kb   = (u16*)(ws + 117440512ull);            // 4 MB
  u16*   Vb   = (u16*)(ws + 121634816ull);            // 4 MB
  u16*   AOb  = (u16*)(ws + 125829120ull);            // 16 MB
  float* cosb = (float*)(ws + 142606336ull);          // 512 KB
  float* sinb = (float*)(ws + 143130624ull);          // 512 KB
  if (ws_size < 143654912ull) return;

  auto cg = [](int n4) { int g = (n4 + 255) / 256; return g > 2048 ? 2048 : g; };
  conv_bf16<<<cg(2097152), 256, 0, stream>>>(x,  xb,  2097152);
  conv_bf16<<<cg(4194304), 256, 0, stream>>>(wq, wqb, 4194304);
  conv_bf16<<<cg(1048576), 256, 0, stream>>>(wk, wkb, 1048576);
  conv_bf16<<<cg(1048576), 256, 0, stream>>>(wv, wvb, 1048576);
  conv_bf16<<<cg(4194304), 256, 0, stream>>>(wo, wob, 4194304);
  rope_table<<<512, 256, 0, stream>>>(cosb, sinb);

  gemm_bt<1><<<dim3(32, 16), 256, 0, stream>>>(xb, wqb, Qb, 2048, 4096, 4096);
  gemm_bt<1><<<dim3(8, 16),  256, 0, stream>>>(xb, wkb, Kb, 2048, 1024, 4096);
  gemm_bt<1><<<dim3(8, 16),  256, 0, stream>>>(xb, wvb, Vb, 2048, 1024, 4096);

  rope_apply<<<16384, 256, 0, stream>>>(Qb, cosb, sinb, NH,  4194304);
  rope_apply<<<4096,  256, 0, stream>>>(Kb, cosb, sinb, NKV, 1048576);

  attn_fwd<<<dim3(32, 32), 256, 0, stream>>>(Qb, Kb, Vb, AOb);

  gemm_bt<0><<<dim3(32, 16), 256, 0, stream>>>(AOb, wob, d_out, 2048, 4096, 4096);
}

// Round 2
// 435.621 us; speedup vs baseline: 1.5969x; 1.5969x over previous
//
#include <hip/hip_runtime.h>

#define S_LEN 2048
#define DIM   4096
#define NH    32
#define NKV   8
#define HD    128

typedef unsigned short u16;
typedef unsigned int   u32;
typedef __bf16 bf16x8 __attribute__((ext_vector_type(8)));
typedef float  f32x4  __attribute__((ext_vector_type(4)));
typedef float  f32x16 __attribute__((ext_vector_type(16)));

__device__ __forceinline__ u16 f2bf(float f) {
  unsigned u = __float_as_uint(f);
  u += 0x7FFFu + ((u >> 16) & 1u);   // RNE
  return (u16)(u >> 16);
}
__device__ __forceinline__ float bf2f(u16 v) {
  return __uint_as_float(((unsigned)v) << 16);
}
__device__ __forceinline__ void async16(void* lds, const void* g) {
  __builtin_amdgcn_global_load_lds((const __attribute__((address_space(1))) void*)g,
                                   (__attribute__((address_space(3))) void*)lds,
                                   16, 0, 0);
}

// ---------------- f32 -> bf16 convert (vectorized) ----------------
__global__ void conv_bf16(const float* __restrict__ in, u16* __restrict__ out, int n4) {
  int stride = gridDim.x * blockDim.x;
  for (int i = blockIdx.x * blockDim.x + threadIdx.x; i < n4; i += stride) {
    float4 v = ((const float4*)in)[i];
    ushort4 o = make_ushort4(f2bf(v.x), f2bf(v.y), f2bf(v.z), f2bf(v.w));
    ((ushort4*)out)[i] = o;
  }
}

// ---------------- RoPE cos/sin table ----------------
__global__ void rope_table(float* __restrict__ cs, float* __restrict__ sn) {
  int idx = blockIdx.x * blockDim.x + threadIdx.x;   // S_LEN*64
  if (idx >= S_LEN * 64) return;
  int i = idx & 63, t = idx >> 6;
  float freq = powf(500000.0f, -(float)(2 * i) / 128.0f);
  float ang = (float)t * freq;
  cs[idx] = cosf(ang);
  sn[idx] = sinf(ang);
}

// ---------------- RoPE in-place on bf16 (seq, nheads*HD) ----------------
__global__ void rope_apply(u16* __restrict__ T, const float* __restrict__ cs,
                           const float* __restrict__ sn, int nheads, int total) {
  int idx = blockIdx.x * blockDim.x + threadIdx.x;
  if (idx >= total) return;
  int i = idx & 63;
  int tmp = idx >> 6;
  int hh = tmp % nheads;
  int t  = tmp / nheads;
  u16* p = T + (size_t)t * (nheads * HD) + hh * HD + 2 * i;
  float c = cs[t * 64 + i], s = sn[t * 64 + i];
  float te = bf2f(p[0]), to = bf2f(p[1]);
  p[0] = f2bf(te * c - to * s);
  p[1] = f2bf(te * s + to * c);
}

// ---------------- bf16 GEMM body: C[m,n] = sum_k A[m,k]*B[n,k] ----------------
// m97-structure: 128x128 tile, BK=32, 4 waves (2x2), 4x4 16x16x32 frags/wave.
template<int OUT_BF16>
__device__ __forceinline__ void gemm_body(const u16* __restrict__ A,
                                          const u16* __restrict__ B,
                                          void* __restrict__ Cout,
                                          int N, int K, int m0, int n0) {
  __shared__ alignas(16) u16 As[128 * 32];
  __shared__ alignas(16) u16 Bs[128 * 32];
  const int tid = threadIdx.x;
  const int w = tid >> 6, l = tid & 63;
  const int lrow = l & 15, lk = l >> 4;
  const int wr = w >> 1, wc = w & 1;
  f32x4 acc[4][4] = {};
  const int srow  = tid >> 2;          // staging row 0..63
  const int scolb = (tid & 3) * 16;    // byte col within 64B row
  const char* Ab = (const char*)A;
  const char* Bb = (const char*)B;
  char* AsB = (char*)As + (size_t)w * 1024;
  char* BsB = (char*)Bs + (size_t)w * 1024;
  const size_t rowskip = (size_t)64 * K * 2;
  for (int k0 = 0; k0 < K; k0 += 32) {
    const char* ga = Ab + ((size_t)(m0 + srow) * K + k0) * 2 + scolb;
    const char* gb = Bb + ((size_t)(n0 + srow) * K + k0) * 2 + scolb;
    async16(AsB,        ga);
    async16(AsB + 4096, ga + rowskip);
    async16(BsB,        gb);
    async16(BsB + 4096, gb + rowskip);
    __syncthreads();
    bf16x8 af[4], bfr[4];
#pragma unroll
    for (int i = 0; i < 4; ++i)
      af[i] = *(const bf16x8*)&As[(wr * 64 + i * 16 + lrow) * 32 + lk * 8];
#pragma unroll
    for (int i = 0; i < 4; ++i)
      bfr[i] = *(const bf16x8*)&Bs[(wc * 64 + i * 16 + lrow) * 32 + lk * 8];
#pragma unroll
    for (int mi = 0; mi < 4; ++mi)
#pragma unroll
      for (int ni = 0; ni < 4; ++ni)
        acc[mi][ni] = __builtin_amdgcn_mfma_f32_16x16x32_bf16(af[mi], bfr[ni], acc[mi][ni], 0, 0, 0);
    __syncthreads();
  }
  // C/D layout (m89-verified): col = lane&15, row = (lane>>4)*4 + j
  if (OUT_BF16) {
    u16* C = (u16*)Cout;
#pragma unroll
    for (int mi = 0; mi < 4; ++mi)
#pragma unroll
      for (int ni = 0; ni < 4; ++ni) {
        int row = m0 + wr * 64 + mi * 16 + lk * 4;
        int col = n0 + wc * 64 + ni * 16 + lrow;
#pragma unroll
        for (int j = 0; j < 4; ++j)
          C[(size_t)(row + j) * N + col] = f2bf(acc[mi][ni][j]);
      }
  } else {
    float* C = (float*)Cout;
#pragma unroll
    for (int mi = 0; mi < 4; ++mi)
#pragma unroll
      for (int ni = 0; ni < 4; ++ni) {
        int row = m0 + wr * 64 + mi * 16 + lk * 4;
        int col = n0 + wc * 64 + ni * 16 + lrow;
#pragma unroll
        for (int j = 0; j < 4; ++j)
          C[(size_t)(row + j) * N + col] = acc[mi][ni][j];
      }
  }
}

template<int OUT_BF16>
__global__ __launch_bounds__(256) void gemm_bt(const u16* __restrict__ A,
                                               const u16* __restrict__ B,
                                               void* __restrict__ Cout,
                                               int M, int N, int K) {
  (void)M;
  gemm_body<OUT_BF16>(A, B, Cout, N, K, blockIdx.y * 128, blockIdx.x * 128);
}

// K-proj and V-proj fused into one launch (better CU utilization)
__global__ __launch_bounds__(256) void gemm_kv(const u16* __restrict__ A,
                                               const u16* __restrict__ Bk,
                                               const u16* __restrict__ Bv,
                                               u16* __restrict__ Ck,
                                               u16* __restrict__ Cv,
                                               int N, int K) {
  const int bx = blockIdx.x;
  const u16* B = (bx < 8) ? Bk : Bv;
  u16* C = (bx < 8) ? Ck : Cv;
  gemm_body<1>(A, B, C, N, K, blockIdx.y * 128, (bx & 7) * 128);
}

// ---------------- flash attention v2: swapped-operand 32x32, causal, GQA ----
// Block: 4 warps x 32 q-rows = 128 q rows. KVBLK = 64. Grid: 512 (16 qtiles x 32 heads).
// QK^T computed as mfma(K, Q): P col = q = lane&31 -> softmax stats per-lane.
// PV computed as mfma(V^T, P^T): O col = q -> rescale/normalize per-lane.
// PV k-order permuted (kappa) so P packs from own regs (no cross-lane exchange);
// V staged transposed in kappa-order so V frags are single b128 reads.
__global__ __launch_bounds__(256, 2) void attn_fwd2(const u16* __restrict__ Q,
                                                    const u16* __restrict__ Km,
                                                    const u16* __restrict__ Vm,
                                                    u16* __restrict__ O) {
  __shared__ alignas(16) u16 Ks[64 * 128];    // [key][d], 256B rows, XOR-swizzled
  __shared__ alignas(16) u16 VTs[128 * 64];   // [d][kappa-pos], 128B rows, XOR-swizzled
  const int tid = threadIdx.x;
  const int w = tid >> 6, lane = tid & 63;
  const int lq = lane & 31, hi = lane >> 5;
  const int bid = blockIdx.x;
  const int head = bid & 31;
  const int g = bid >> 5;
  const int qt = (g < 8) ? (15 - g) : (g - 8);   // long tiles dispatched first
  const int qt0 = qt * 128;
  const int hk = head >> 2;
  const float scale = 0.08838834764831845f;      // 1/sqrt(128)
  const int qw = qt0 + w * 32;                   // warp q base
  const int qrow = qw + lq;                      // this lane's q (column index)

  // Q fragments (B-operand): col=q, chunk c covers d = c*16 + hi*8 + 0..7
  bf16x8 qf[8];
  {
    const u16* qp = Q + (size_t)qrow * DIM + head * HD + hi * 8;
#pragma unroll
    for (int c = 0; c < 8; ++c)
      qf[c] = *(const bf16x8*)&qp[c * 16];
  }
  f32x16 o_acc[4] = {};    // o_acc[dt]: rows d = dt*32 + (r&3)+8*(r>>2)+4*hi, col q
  float m_r = -3.0e38f, l_r = 0.f;

  const int NT = qt0 / 64 + 2;
  for (int t = 0; t < NT; ++t) {
    const int j0 = t * 64;
    // ---- stage K: 16KB via global_load_lds, source pre-swizzled ----
#pragma unroll
    for (int it = 0; it < 4; ++it) {
      int idx = it * 256 + tid;
      int row = idx >> 4, s16 = idx & 15;
      const char* src = (const char*)(Km + (size_t)(j0 + row) * (NKV * HD) + hk * HD)
                        + ((s16 * 16) ^ ((row & 7) << 4));
      async16((char*)Ks + idx * 16, src);
    }
    // ---- stage V transposed into kappa-order ----
    {
      int vr = lane;                                        // key row 0..63
      int pos = (vr & ~12) | ((vr & 4) << 1) | ((vr & 8) >> 1);  // kappa position
#pragma unroll
      for (int it = 0; it < 4; ++it) {
        int db = w * 32 + it * 8;
        const u16* vp = Vm + (size_t)(j0 + vr) * (NKV * HD) + hk * HD + db;
        uint4 raw = *(const uint4*)vp;
        const u16* pe = (const u16*)&raw;
#pragma unroll
        for (int e = 0; e < 8; ++e) {
          int d = db + e;
          *(u16*)((char*)VTs + d * 128 + ((pos * 2) ^ ((d & 7) << 4))) = pe[e];
        }
      }
    }
    __syncthreads();   // drains vmcnt+lgkmcnt (compiler-inserted)
    if (j0 <= qw + 31) {
      // ---- QK^T (swapped): s[kb] rows = keys kb*32+.., cols = q ----
      f32x16 s0 = {}, s1 = {};
      const int kswz = (lq & 7) << 4;
#pragma unroll
      for (int c = 0; c < 8; ++c) {
        int cb = c * 32 + hi * 16;
        bf16x8 k0 = *(const bf16x8*)((const char*)Ks + lq * 256 + (cb ^ kswz));
        bf16x8 k1 = *(const bf16x8*)((const char*)Ks + (32 + lq) * 256 + (cb ^ kswz));
        s0 = __builtin_amdgcn_mfma_f32_32x32x16_bf16(k0, qf[c], s0, 0, 0, 0);
        s1 = __builtin_amdgcn_mfma_f32_32x32x16_bf16(k1, qf[c], s1, 0, 0, 0);
      }
      // ---- softmax (per-lane: lane owns column q) ----
      float p0[16], p1[16];
      float tm = -3.0e38f;
      const bool domask = (j0 + 63 > qw);
#pragma unroll
      for (int r = 0; r < 16; ++r) {
        int kk = (r & 3) + 8 * (r >> 2) + 4 * hi;   // key row within 32-block
        float a = s0[r] * scale;
        float b = s1[r] * scale;
        if (domask) {
          if (j0 + kk > qrow)      a = -3.0e38f;
          if (j0 + 32 + kk > qrow) b = -3.0e38f;
        }
        p0[r] = a; p1[r] = b;
        tm = fmaxf(tm, fmaxf(a, b));
      }
      tm = fmaxf(tm, __shfl_xor(tm, 32));           // combine key-halves (same q)
      float mnew = fmaxf(m_r, tm);
      float corr = __expf(m_r - mnew);
      m_r = mnew;
      float rs = 0.f;
#pragma unroll
      for (int r = 0; r < 16; ++r) {
        p0[r] = __expf(p0[r] - mnew);
        p1[r] = __expf(p1[r] - mnew);
        rs += p0[r] + p1[r];
      }
      rs += __shfl_xor(rs, 32);
      l_r = l_r * corr + rs;
#pragma unroll
      for (int dt = 0; dt < 4; ++dt)
#pragma unroll
        for (int r = 0; r < 16; ++r) o_acc[dt][r] *= corr;
      // ---- pack P (own-lane kappa order): chunk c <- p[kb=c>>1][8*(c&1)+0..7] ----
      uint4 pk[4];
#pragma unroll
      for (int cc = 0; cc < 2; ++cc) {
        asm("v_cvt_pk_bf16_f32 %0, %1, %2" : "=v"(pk[cc].x)     : "v"(p0[8*cc+0]), "v"(p0[8*cc+1]));
        asm("v_cvt_pk_bf16_f32 %0, %1, %2" : "=v"(pk[cc].y)     : "v"(p0[8*cc+2]), "v"(p0[8*cc+3]));
        asm("v_cvt_pk_bf16_f32 %0, %1, %2" : "=v"(pk[cc].z)     : "v"(p0[8*cc+4]), "v"(p0[8*cc+5]));
        asm("v_cvt_pk_bf16_f32 %0, %1, %2" : "=v"(pk[cc].w)     : "v"(p0[8*cc+6]), "v"(p0[8*cc+7]));
        asm("v_cvt_pk_bf16_f32 %0, %1, %2" : "=v"(pk[2+cc].x)   : "v"(p1[8*cc+0]), "v"(p1[8*cc+1]));
        asm("v_cvt_pk_bf16_f32 %0, %1, %2" : "=v"(pk[2+cc].y)   : "v"(p1[8*cc+2]), "v"(p1[8*cc+3]));
        asm("v_cvt_pk_bf16_f32 %0, %1, %2" : "=v"(pk[2+cc].z)   : "v"(p1[8*cc+4]), "v"(p1[8*cc+5]));
        asm("v_cvt_pk_bf16_f32 %0, %1, %2" : "=v"(pk[2+cc].w)   : "v"(p1[8*cc+6]), "v"(p1[8*cc+7]));
      }
      // ---- PV: O[dt] += mfma(V^T-frag, P^T-frag) over 4 kappa-chunks ----
#pragma unroll
      for (int dt = 0; dt < 4; ++dt) {
        const char* vrow = (const char*)VTs + (dt * 32 + lq) * 128;
#pragma unroll
        for (int c = 0; c < 4; ++c) {
          bf16x8 vf = *(const bf16x8*)(vrow + ((c * 32 + hi * 16) ^ kswz));
          bf16x8 pf = __builtin_bit_cast(bf16x8, pk[c]);
          o_acc[dt] = __builtin_amdgcn_mfma_f32_32x32x16_bf16(vf, pf, o_acc[dt], 0, 0, 0);
        }
      }
    }
    __syncthreads();
  }
  // ---- normalize (per-lane) + write: regs 4rq+0..3 = consecutive d ----
  float inv = 1.0f / l_r;
  u16* op = O + (size_t)qrow * DIM + head * HD;
#pragma unroll
  for (int dt = 0; dt < 4; ++dt)
#pragma unroll
    for (int rq = 0; rq < 4; ++rq) {
      int d0 = dt * 32 + 8 * rq + 4 * hi;
      ushort4 o4;
      o4.x = f2bf(o_acc[dt][4 * rq + 0] * inv);
      o4.y = f2bf(o_acc[dt][4 * rq + 1] * inv);
      o4.z = f2bf(o_acc[dt][4 * rq + 2] * inv);
      o4.w = f2bf(o_acc[dt][4 * rq + 3] * inv);
      *(ushort4*)&op[d0] = o4;
    }
}

// ---------------- host launcher ----------------
extern "C" void kernel_launch(void* const* d_in, const int* in_sizes, int n_in,
                              void* d_out, int out_size, void* d_ws, size_t ws_size,
                              hipStream_t stream) {
  (void)in_sizes; (void)n_in; (void)out_size;
  const float* x  = (const float*)d_in[0];
  const float* wq = (const float*)d_in[2];
  const float* wk = (const float*)d_in[3];
  const float* wv = (const float*)d_in[4];
  const float* wo = (const float*)d_in[5];

  char* ws = (char*)d_ws;
  u16*   xb   = (u16*)(ws + 0);                       // 16 MB
  u16*   wqb  = (u16*)(ws + 16777216ull);             // 32 MB
  u16*   wkb  = (u16*)(ws + 50331648ull);             // 8 MB
  u16*   wvb  = (u16*)(ws + 58720256ull);             // 8 MB
  u16*   wob  = (u16*)(ws + 67108864ull);             // 32 MB
  u16*   Qb   = (u16*)(ws + 100663296ull);            // 16 MB
  u16*   Kb   = (u16*)(ws + 117440512ull);            // 4 MB
  u16*   Vb   = (u16*)(ws + 121634816ull);            // 4 MB
  u16*   AOb  = (u16*)(ws + 125829120ull);            // 16 MB
  float* cosb = (float*)(ws + 142606336ull);          // 512 KB
  float* sinb = (float*)(ws + 143130624ull);          // 512 KB
  if (ws_size < 143654912ull) return;

  auto cg = [](int n4) { int g = (n4 + 255) / 256; return g > 2048 ? 2048 : g; };
  conv_bf16<<<cg(2097152), 256, 0, stream>>>(x,  xb,  2097152);
  conv_bf16<<<cg(4194304), 256, 0, stream>>>(wq, wqb, 4194304);
  conv_bf16<<<cg(1048576), 256, 0, stream>>>(wk, wkb, 1048576);
  conv_bf16<<<cg(1048576), 256, 0, stream>>>(wv, wvb, 1048576);
  conv_bf16<<<cg(4194304), 256, 0, stream>>>(wo, wob, 4194304);
  rope_table<<<512, 256, 0, stream>>>(cosb, sinb);

  gemm_bt<1><<<dim3(32, 16), 256, 0, stream>>>(xb, wqb, Qb, 2048, 4096, 4096);
  gemm_kv<<<dim3(16, 16), 256, 0, stream>>>(xb, wkb, wvb, Kb, Vb, 1024, 4096);

  rope_apply<<<16384, 256, 0, stream>>>(Qb, cosb, sinb, NH,  4194304);
  rope_apply<<<4096,  256, 0, stream>>>(Kb, cosb, sinb, NKV, 1048576);

  attn_fwd2<<<512, 256, 0, stream>>>(Qb, Kb, Vb, AOb);

  gemm_bt<0><<<dim3(32, 16), 256, 0, stream>>>(AOb, wob, d_out, 2048, 4096, 4096);
}

// Round 3
// 347.115 us; speedup vs baseline: 2.0041x; 1.2550x over previous
//
#include <hip/hip_runtime.h>

#define S_LEN 2048
#define DIM   4096
#define NH    32
#define NKV   8
#define HD    128

typedef unsigned short u16;
typedef unsigned int   u32;
typedef __bf16 bf16x8 __attribute__((ext_vector_type(8)));
typedef float  f32x4  __attribute__((ext_vector_type(4)));
typedef float  f32x16 __attribute__((ext_vector_type(16)));

__device__ __forceinline__ u16 f2bf(float f) {
  unsigned u = __float_as_uint(f);
  u += 0x7FFFu + ((u >> 16) & 1u);   // RNE
  return (u16)(u >> 16);
}
__device__ __forceinline__ float bf2f(u16 v) {
  return __uint_as_float(((unsigned)v) << 16);
}
__device__ __forceinline__ void async16(void* lds, const void* g) {
  __builtin_amdgcn_global_load_lds((const __attribute__((address_space(1))) void*)g,
                                   (__attribute__((address_space(3))) void*)lds,
                                   16, 0, 0);
}
#define MFMA16(a, b, c) __builtin_amdgcn_mfma_f32_16x16x32_bf16((a), (b), (c), 0, 0, 0)

// ---------------- f32 -> bf16 convert (vectorized) ----------------
__global__ void conv_bf16(const float* __restrict__ in, u16* __restrict__ out, int n4) {
  int stride = gridDim.x * blockDim.x;
  for (int i = blockIdx.x * blockDim.x + threadIdx.x; i < n4; i += stride) {
    float4 v = ((const float4*)in)[i];
    ushort4 o = make_ushort4(f2bf(v.x), f2bf(v.y), f2bf(v.z), f2bf(v.w));
    ((ushort4*)out)[i] = o;
  }
}

// ---------------- RoPE cos/sin table ----------------
__global__ void rope_table(float* __restrict__ cs, float* __restrict__ sn) {
  int idx = blockIdx.x * blockDim.x + threadIdx.x;   // S_LEN*64
  if (idx >= S_LEN * 64) return;
  int i = idx & 63, t = idx >> 6;
  float freq = powf(500000.0f, -(float)(2 * i) / 128.0f);
  float ang = (float)t * freq;
  cs[idx] = cosf(ang);
  sn[idx] = sinf(ang);
}

// ---------------- RoPE in-place on bf16 (seq, nheads*HD) ----------------
__global__ void rope_apply(u16* __restrict__ T, const float* __restrict__ cs,
                           const float* __restrict__ sn, int nheads, int total) {
  int idx = blockIdx.x * blockDim.x + threadIdx.x;
  if (idx >= total) return;
  int i = idx & 63;
  int tmp = idx >> 6;
  int hh = tmp % nheads;
  int t  = tmp / nheads;
  u16* p = T + (size_t)t * (nheads * HD) + hh * HD + 2 * i;
  float c = cs[t * 64 + i], s = sn[t * 64 + i];
  float te = bf2f(p[0]), to = bf2f(p[1]);
  p[0] = f2bf(te * c - to * s);
  p[1] = f2bf(te * s + to * c);
}

// ============ 256x256 8-wave 4-phase GEMM, BK=64, counted vmcnt ============
// C[m,n] = sum_k A[m,k] * B[n,k].  512 thr = 8 waves (wr in {0,1}, wc in {0..3}).
// Phase = block C-quadrant (A-half qa x B-half qb); all 8 waves cooperate.
// LDS 128KB: 2 buffers x (A: 2x16KB halves + B: 2x16KB halves), row-major
// [128][64] bf16 per half, 16B-slot swizzle slot^=(row&7) (both-sides: linear
// global_load_lds dest + pre-swizzled global source; swizzled ds_read).
template<int OUT_BF16>
__device__ __forceinline__ void gemm256_body(const u16* __restrict__ A,
                                             const u16* __restrict__ Bm,
                                             void* __restrict__ Cout,
                                             int m0, int n0, int Nst,
                                             int Ks, int Kiter) {
  __shared__ alignas(16) u16 lds[65536];
  const int tid = threadIdx.x;
  const int w = tid >> 6, lane = tid & 63;
  const int lrow = lane & 15, lk = lane >> 4;
  const int wr = w >> 2, wc = w & 3;
  f32x4 acc[2][2][4][2] = {};

  const int srow = tid >> 3;                 // staging row 0..63 (and +64)
  const int scol = (tid & 7) ^ (srow & 7);   // pre-swizzled source 16B slot
  const u16* Ag = A + (size_t)m0 * Ks;
  const u16* Bg = Bm + (size_t)n0 * Ks;

  const int sl0 = (lk ^ (lrow & 7)) * 8;           // kk=0 swizzled slot (u16)
  const int sl1 = ((4 + lk) ^ (lrow & 7)) * 8;     // kk=1
  const int aro = (wr * 64 + lrow) * 64;           // + mi*1024
  const int bro = (wc * 32 + lrow) * 64;           // + ni*1024

  const int nkt = Kiter >> 6;

#define STAGE_H(dst_u16, gbase) do { \
    const u16* _g = (gbase) + (size_t)srow * Ks + scol * 8; \
    async16(&lds[(dst_u16) + tid * 8], _g); \
    async16(&lds[(dst_u16) + tid * 8 + 4096], _g + (size_t)64 * Ks); \
  } while (0)
#define VM4 asm volatile("s_waitcnt vmcnt(4)" ::: "memory")
#define VM0 asm volatile("s_waitcnt vmcnt(0)" ::: "memory")
#define BARX __builtin_amdgcn_s_barrier()

  // prologue: tile 0 halves in stage order A0, B0, B1, A1
  STAGE_H(0,     Ag);
  STAGE_H(16384, Bg);
  STAGE_H(24576, Bg + (size_t)128 * Ks);
  STAGE_H(8192,  Ag + (size_t)128 * Ks);
  VM4;        // A0(0), B0(0) landed
  BARX;

  bf16x8 af[4][2], bfa[2][2], bfb[2][2];
  for (int t = 0; t < nkt; ++t) {
    const int cb = (t & 1) << 15;
    const int sb = cb ^ 32768;
    const u16* An = Ag + (t + 1) * 64;
    const u16* Bn = Bg + (t + 1) * 64;
    const bool st = (t + 1 < nkt);
    // ---- P0: quadrant (qa=0, qb=0); stage A0(t+1) ----
    {
      const u16* pa = &lds[cb];
      const u16* pb = &lds[cb + 16384];
#pragma unroll
      for (int mi = 0; mi < 4; ++mi) {
        af[mi][0] = *(const bf16x8*)&pa[aro + mi * 1024 + sl0];
        af[mi][1] = *(const bf16x8*)&pa[aro + mi * 1024 + sl1];
      }
#pragma unroll
      for (int ni = 0; ni < 2; ++ni) {
        bfa[ni][0] = *(const bf16x8*)&pb[bro + ni * 1024 + sl0];
        bfa[ni][1] = *(const bf16x8*)&pb[bro + ni * 1024 + sl1];
      }
      if (st) { STAGE_H(sb, An); VM4; } else { VM0; }
      BARX;
      __builtin_amdgcn_s_setprio(1);
#pragma unroll
      for (int mi = 0; mi < 4; ++mi)
#pragma unroll
        for (int ni = 0; ni < 2; ++ni) {
          acc[0][0][mi][ni] = MFMA16(af[mi][0], bfa[ni][0], acc[0][0][mi][ni]);
          acc[0][0][mi][ni] = MFMA16(af[mi][1], bfa[ni][1], acc[0][0][mi][ni]);
        }
      __builtin_amdgcn_s_setprio(0);
      BARX;
    }
    // ---- P1: (0,1); stage B0(t+1) ----
    {
      const u16* pb = &lds[cb + 24576];
#pragma unroll
      for (int ni = 0; ni < 2; ++ni) {
        bfb[ni][0] = *(const bf16x8*)&pb[bro + ni * 1024 + sl0];
        bfb[ni][1] = *(const bf16x8*)&pb[bro + ni * 1024 + sl1];
      }
      if (st) { STAGE_H(sb + 16384, Bn); VM4; } else { VM0; }
      BARX;
      __builtin_amdgcn_s_setprio(1);
#pragma unroll
      for (int mi = 0; mi < 4; ++mi)
#pragma unroll
        for (int ni = 0; ni < 2; ++ni) {
          acc[0][1][mi][ni] = MFMA16(af[mi][0], bfb[ni][0], acc[0][1][mi][ni]);
          acc[0][1][mi][ni] = MFMA16(af[mi][1], bfb[ni][1], acc[0][1][mi][ni]);
        }
      __builtin_amdgcn_s_setprio(0);
      BARX;
    }
    // ---- P2: (1,1); stage B1(t+1) ----
    {
      const u16* pa = &lds[cb + 8192];
#pragma unroll
      for (int mi = 0; mi < 4; ++mi) {
        af[mi][0] = *(const bf16x8*)&pa[aro + mi * 1024 + sl0];
        af[mi][1] = *(const bf16x8*)&pa[aro + mi * 1024 + sl1];
      }
      if (st) { STAGE_H(sb + 24576, Bn + (size_t)128 * Ks); VM4; } else { VM0; }
      BARX;
      __builtin_amdgcn_s_setprio(1);
#pragma unroll
      for (int mi = 0; mi < 4; ++mi)
#pragma unroll
        for (int ni = 0; ni < 2; ++ni) {
          acc[1][1][mi][ni] = MFMA16(af[mi][0], bfb[ni][0], acc[1][1][mi][ni]);
          acc[1][1][mi][ni] = MFMA16(af[mi][1], bfb[ni][1], acc[1][1][mi][ni]);
        }
      __builtin_amdgcn_s_setprio(0);
      BARX;
    }
    // ---- P3: (1,0); stage A1(t+1) ----
    {
      const u16* pb = &lds[cb + 16384];
#pragma unroll
      for (int ni = 0; ni < 2; ++ni) {
        bfa[ni][0] = *(const bf16x8*)&pb[bro + ni * 1024 + sl0];
        bfa[ni][1] = *(const bf16x8*)&pb[bro + ni * 1024 + sl1];
      }
      if (st) { STAGE_H(sb + 8192, An + (size_t)128 * Ks); VM4; } else { VM0; }
      BARX;
      __builtin_amdgcn_s_setprio(1);
#pragma unroll
      for (int mi = 0; mi < 4; ++mi)
#pragma unroll
        for (int ni = 0; ni < 2; ++ni) {
          acc[1][0][mi][ni] = MFMA16(af[mi][0], bfa[ni][0], acc[1][0][mi][ni]);
          acc[1][0][mi][ni] = MFMA16(af[mi][1], bfa[ni][1], acc[1][0][mi][ni]);
        }
      __builtin_amdgcn_s_setprio(0);
      BARX;
    }
  }
#undef STAGE_H
#undef VM4
#undef VM0
#undef BARX
  // ---- epilogue: C/D layout col=lane&15, row=(lane>>4)*4+j (m89-verified) ----
#pragma unroll
  for (int qa = 0; qa < 2; ++qa)
#pragma unroll
    for (int qb = 0; qb < 2; ++qb)
#pragma unroll
      for (int mi = 0; mi < 4; ++mi)
#pragma unroll
        for (int ni = 0; ni < 2; ++ni) {
          int row = m0 + qa * 128 + wr * 64 + mi * 16 + lk * 4;
          int col = n0 + qb * 128 + wc * 32 + ni * 16 + lrow;
          if (OUT_BF16) {
            u16* C = (u16*)Cout;
#pragma unroll
            for (int j = 0; j < 4; ++j)
              C[(size_t)(row + j) * Nst + col] = f2bf(acc[qa][qb][mi][ni][j]);
          } else {
            float* C = (float*)Cout;
#pragma unroll
            for (int j = 0; j < 4; ++j)
              C[(size_t)(row + j) * Nst + col] = acc[qa][qb][mi][ni][j];
          }
        }
}

// fused QKV projection: grid (24, 8)
__global__ __launch_bounds__(512, 2) void gemm256_qkv(const u16* __restrict__ xb,
                                                      const u16* __restrict__ wqb,
                                                      const u16* __restrict__ wkb,
                                                      const u16* __restrict__ wvb,
                                                      u16* __restrict__ Qb,
                                                      u16* __restrict__ Kb,
                                                      u16* __restrict__ Vb) {
  const int bx = blockIdx.x, by = blockIdx.y;
  const u16* B; u16* C; int n0, Nst;
  if (bx < 16)      { B = wqb; C = Qb; n0 = bx * 256;        Nst = 4096; }
  else if (bx < 20) { B = wkb; C = Kb; n0 = (bx - 16) * 256; Nst = 1024; }
  else              { B = wvb; C = Vb; n0 = (bx - 20) * 256; Nst = 1024; }
  gemm256_body<1>(xb, B, C, by * 256, n0, Nst, 4096, 4096);
}

// output projection, K split in 2 (deterministic two-buffer partials): grid (16, 8, 2)
__global__ __launch_bounds__(512, 2) void gemm256_wo(const u16* __restrict__ AOb,
                                                     const u16* __restrict__ wob,
                                                     float* __restrict__ P0,
                                                     float* __restrict__ P1) {
  const int z = blockIdx.z;
  float* P = z ? P1 : P0;
  gemm256_body<0>(AOb + z * 2048, wob + z * 2048, P,
                  blockIdx.y * 256, blockIdx.x * 256, 4096, 4096, 2048);
}

__global__ void add_f32(const float* __restrict__ a, const float* __restrict__ b,
                        float* __restrict__ o, int n4) {
  int stride = gridDim.x * blockDim.x;
  for (int i = blockIdx.x * blockDim.x + threadIdx.x; i < n4; i += stride) {
    float4 va = ((const float4*)a)[i];
    float4 vb = ((const float4*)b)[i];
    ((float4*)o)[i] = make_float4(va.x + vb.x, va.y + vb.y, va.z + vb.z, va.w + vb.w);
  }
}

// ---------------- flash attention: swapped-operand 32x32, causal, GQA ----
__global__ __launch_bounds__(256, 2) void attn_fwd2(const u16* __restrict__ Q,
                                                    const u16* __restrict__ Km,
                                                    const u16* __restrict__ Vm,
                                                    u16* __restrict__ O) {
  __shared__ alignas(16) u16 Ks[64 * 128];    // [key][d], 256B rows, XOR-swizzled
  __shared__ alignas(16) u16 VTs[128 * 64];   // [d][kappa-pos], 128B rows, XOR-swizzled
  const int tid = threadIdx.x;
  const int w = tid >> 6, lane = tid & 63;
  const int lq = lane & 31, hi = lane >> 5;
  const int bid = blockIdx.x;
  const int head = bid & 31;
  const int g = bid >> 5;
  const int qt = (g < 8) ? (15 - g) : (g - 8);   // long tiles dispatched first
  const int qt0 = qt * 128;
  const int hk = head >> 2;
  const float scale = 0.08838834764831845f;      // 1/sqrt(128)
  const int qw = qt0 + w * 32;                   // warp q base
  const int qrow = qw + lq;                      // this lane's q (column index)

  // Q fragments (B-operand): col=q, chunk c covers d = c*16 + hi*8 + 0..7
  bf16x8 qf[8];
  {
    const u16* qp = Q + (size_t)qrow * DIM + head * HD + hi * 8;
#pragma unroll
    for (int c = 0; c < 8; ++c)
      qf[c] = *(const bf16x8*)&qp[c * 16];
  }
  f32x16 o_acc[4] = {};    // o_acc[dt]: rows d = dt*32 + (r&3)+8*(r>>2)+4*hi, col q
  float m_r = -3.0e38f, l_r = 0.f;

  const int NT = qt0 / 64 + 2;
  for (int t = 0; t < NT; ++t) {
    const int j0 = t * 64;
    // ---- stage K: 16KB via global_load_lds, source pre-swizzled ----
#pragma unroll
    for (int it = 0; it < 4; ++it) {
      int idx = it * 256 + tid;
      int row = idx >> 4, s16 = idx & 15;
      const char* src = (const char*)(Km + (size_t)(j0 + row) * (NKV * HD) + hk * HD)
                        + ((s16 * 16) ^ ((row & 7) << 4));
      async16((char*)Ks + idx * 16, src);
    }
    // ---- stage V transposed into kappa-order ----
    {
      int vr = lane;                                        // key row 0..63
      int pos = (vr & ~12) | ((vr & 4) << 1) | ((vr & 8) >> 1);  // kappa position
#pragma unroll
      for (int it = 0; it < 4; ++it) {
        int db = w * 32 + it * 8;
        const u16* vp = Vm + (size_t)(j0 + vr) * (NKV * HD) + hk * HD + db;
        uint4 raw = *(const uint4*)vp;
        const u16* pe = (const u16*)&raw;
#pragma unroll
        for (int e = 0; e < 8; ++e) {
          int d = db + e;
          *(u16*)((char*)VTs + d * 128 + ((pos * 2) ^ ((d & 7) << 4))) = pe[e];
        }
      }
    }
    __syncthreads();
    if (j0 <= qw + 31) {
      // ---- QK^T (swapped): s rows = keys, cols = q ----
      f32x16 s0 = {}, s1 = {};
      const int kswz = (lq & 7) << 4;
#pragma unroll
      for (int c = 0; c < 8; ++c) {
        int cbv = c * 32 + hi * 16;
        bf16x8 k0 = *(const bf16x8*)((const char*)Ks + lq * 256 + (cbv ^ kswz));
        bf16x8 k1 = *(const bf16x8*)((const char*)Ks + (32 + lq) * 256 + (cbv ^ kswz));
        s0 = __builtin_amdgcn_mfma_f32_32x32x16_bf16(k0, qf[c], s0, 0, 0, 0);
        s1 = __builtin_amdgcn_mfma_f32_32x32x16_bf16(k1, qf[c], s1, 0, 0, 0);
      }
      // ---- softmax (per-lane: lane owns column q) ----
      float p0[16], p1[16];
      float tm = -3.0e38f;
      const bool domask = (j0 + 63 > qw);
#pragma unroll
      for (int r = 0; r < 16; ++r) {
        int kk = (r & 3) + 8 * (r >> 2) + 4 * hi;
        float a = s0[r] * scale;
        float b = s1[r] * scale;
        if (domask) {
          if (j0 + kk > qrow)      a = -3.0e38f;
          if (j0 + 32 + kk > qrow) b = -3.0e38f;
        }
        p0[r] = a; p1[r] = b;
        tm = fmaxf(tm, fmaxf(a, b));
      }
      tm = fmaxf(tm, __shfl_xor(tm, 32));
      float mnew = fmaxf(m_r, tm);
      float corr = __expf(m_r - mnew);
      m_r = mnew;
      float rs = 0.f;
#pragma unroll
      for (int r = 0; r < 16; ++r) {
        p0[r] = __expf(p0[r] - mnew);
        p1[r] = __expf(p1[r] - mnew);
        rs += p0[r] + p1[r];
      }
      rs += __shfl_xor(rs, 32);
      l_r = l_r * corr + rs;
#pragma unroll
      for (int dt = 0; dt < 4; ++dt)
#pragma unroll
        for (int r = 0; r < 16; ++r) o_acc[dt][r] *= corr;
      // ---- pack P (own-lane kappa order) ----
      uint4 pk[4];
#pragma unroll
      for (int cc = 0; cc < 2; ++cc) {
        asm("v_cvt_pk_bf16_f32 %0, %1, %2" : "=v"(pk[cc].x)     : "v"(p0[8*cc+0]), "v"(p0[8*cc+1]));
        asm("v_cvt_pk_bf16_f32 %0, %1, %2" : "=v"(pk[cc].y)     : "v"(p0[8*cc+2]), "v"(p0[8*cc+3]));
        asm("v_cvt_pk_bf16_f32 %0, %1, %2" : "=v"(pk[cc].z)     : "v"(p0[8*cc+4]), "v"(p0[8*cc+5]));
        asm("v_cvt_pk_bf16_f32 %0, %1, %2" : "=v"(pk[cc].w)     : "v"(p0[8*cc+6]), "v"(p0[8*cc+7]));
        asm("v_cvt_pk_bf16_f32 %0, %1, %2" : "=v"(pk[2+cc].x)   : "v"(p1[8*cc+0]), "v"(p1[8*cc+1]));
        asm("v_cvt_pk_bf16_f32 %0, %1, %2" : "=v"(pk[2+cc].y)   : "v"(p1[8*cc+2]), "v"(p1[8*cc+3]));
        asm("v_cvt_pk_bf16_f32 %0, %1, %2" : "=v"(pk[2+cc].z)   : "v"(p1[8*cc+4]), "v"(p1[8*cc+5]));
        asm("v_cvt_pk_bf16_f32 %0, %1, %2" : "=v"(pk[2+cc].w)   : "v"(p1[8*cc+6]), "v"(p1[8*cc+7]));
      }
      // ---- PV: O[dt] += mfma(V^T-frag, P^T-frag) ----
#pragma unroll
      for (int dt = 0; dt < 4; ++dt) {
        const char* vrow = (const char*)VTs + (dt * 32 + lq) * 128;
#pragma unroll
        for (int c = 0; c < 4; ++c) {
          bf16x8 vf = *(const bf16x8*)(vrow + ((c * 32 + hi * 16) ^ kswz));
          bf16x8 pf = __builtin_bit_cast(bf16x8, pk[c]);
          o_acc[dt] = __builtin_amdgcn_mfma_f32_32x32x16_bf16(vf, pf, o_acc[dt], 0, 0, 0);
        }
      }
    }
    __syncthreads();
  }
  // ---- normalize + write ----
  float inv = 1.0f / l_r;
  u16* op = O + (size_t)qrow * DIM + head * HD;
#pragma unroll
  for (int dt = 0; dt < 4; ++dt)
#pragma unroll
    for (int rq = 0; rq < 4; ++rq) {
      int d0 = dt * 32 + 8 * rq + 4 * hi;
      ushort4 o4;
      o4.x = f2bf(o_acc[dt][4 * rq + 0] * inv);
      o4.y = f2bf(o_acc[dt][4 * rq + 1] * inv);
      o4.z = f2bf(o_acc[dt][4 * rq + 2] * inv);
      o4.w = f2bf(o_acc[dt][4 * rq + 3] * inv);
      *(ushort4*)&op[d0] = o4;
    }
}

// ---------------- host launcher ----------------
extern "C" void kernel_launch(void* const* d_in, const int* in_sizes, int n_in,
                              void* d_out, int out_size, void* d_ws, size_t ws_size,
                              hipStream_t stream) {
  (void)in_sizes; (void)n_in; (void)out_size;
  const float* x  = (const float*)d_in[0];
  const float* wq = (const float*)d_in[2];
  const float* wk = (const float*)d_in[3];
  const float* wv = (const float*)d_in[4];
  const float* wo = (const float*)d_in[5];

  char* ws = (char*)d_ws;
  u16*   xb   = (u16*)(ws + 0);                       // 16 MB (dead after QKV gemm)
  u16*   wqb  = (u16*)(ws + 16777216ull);             // 32 MB (dead after QKV gemm)
  u16*   wkb  = (u16*)(ws + 50331648ull);             // 8 MB
  u16*   wvb  = (u16*)(ws + 58720256ull);             // 8 MB
  u16*   wob  = (u16*)(ws + 67108864ull);             // 32 MB
  u16*   Qb   = (u16*)(ws + 100663296ull);            // 16 MB
  u16*   Kb   = (u16*)(ws + 117440512ull);            // 4 MB
  u16*   Vb   = (u16*)(ws + 121634816ull);            // 4 MB
  u16*   AOb  = (u16*)(ws + 125829120ull);            // 16 MB
  float* cosb = (float*)(ws + 142606336ull);          // 512 KB
  float* sinb = (float*)(ws + 143130624ull);          // 512 KB
  // wo-partials overlay regions dead by the time gemm256_wo runs:
  float* P0   = (float*)(ws + 0);                     // 32 MB (xb + wqb lower)
  float* P1   = (float*)(ws + 33554432ull);           // 32 MB (wqb upper + wkb + wvb)
  if (ws_size < 143654912ull) return;

  auto cg = [](int n4) { int g = (n4 + 255) / 256; return g > 2048 ? 2048 : g; };
  conv_bf16<<<cg(2097152), 256, 0, stream>>>(x,  xb,  2097152);
  conv_bf16<<<cg(4194304), 256, 0, stream>>>(wq, wqb, 4194304);
  conv_bf16<<<cg(1048576), 256, 0, stream>>>(wk, wkb, 1048576);
  conv_bf16<<<cg(1048576), 256, 0, stream>>>(wv, wvb, 1048576);
  conv_bf16<<<cg(4194304), 256, 0, stream>>>(wo, wob, 4194304);
  rope_table<<<512, 256, 0, stream>>>(cosb, sinb);

  gemm256_qkv<<<dim3(24, 8), 512, 0, stream>>>(xb, wqb, wkb, wvb, Qb, Kb, Vb);

  rope_apply<<<16384, 256, 0, stream>>>(Qb, cosb, sinb, NH,  4194304);
  rope_apply<<<4096,  256, 0, stream>>>(Kb, cosb, sinb, NKV, 1048576);

  attn_fwd2<<<512, 256, 0, stream>>>(Qb, Kb, Vb, AOb);

  gemm256_wo<<<dim3(16, 8, 2), 512, 0, stream>>>(AOb, wob, P0, P1);
  add_f32<<<2048, 256, 0, stream>>>(P0, P1, (float*)d_out, 2097152);
}

// Round 4
// 327.946 us; speedup vs baseline: 2.1212x; 1.0585x over previous
//
#include <hip/hip_runtime.h>

#define S_LEN 2048
#define DIM   4096
#define NH    32
#define NKV   8
#define HD    128
#define QST   6144   // packed QKV row stride (Q | K | V)

typedef unsigned short u16;
typedef unsigned int   u32;
typedef __bf16 bf16x8 __attribute__((ext_vector_type(8)));
typedef float  f32x4  __attribute__((ext_vector_type(4)));
typedef float  f32x16 __attribute__((ext_vector_type(16)));

__device__ __forceinline__ u16 f2bf(float f) {
  unsigned u = __float_as_uint(f);
  u += 0x7FFFu + ((u >> 16) & 1u);   // RNE
  return (u16)(u >> 16);
}
__device__ __forceinline__ float bf2f(u16 v) {
  return __uint_as_float(((unsigned)v) << 16);
}
__device__ __forceinline__ void async16(void* lds, const void* g) {
  __builtin_amdgcn_global_load_lds((const __attribute__((address_space(1))) void*)g,
                                   (__attribute__((address_space(3))) void*)lds,
                                   16, 0, 0);
}
#define MFMA16(a, b, c) __builtin_amdgcn_mfma_f32_16x16x32_bf16((a), (b), (c), 0, 0, 0)

// ---------------- f32 -> bf16 convert (vectorized) ----------------
__global__ void conv_bf16(const float* __restrict__ in, u16* __restrict__ out, int n4) {
  int stride = gridDim.x * blockDim.x;
  for (int i = blockIdx.x * blockDim.x + threadIdx.x; i < n4; i += stride) {
    float4 v = ((const float4*)in)[i];
    ushort4 o = make_ushort4(f2bf(v.x), f2bf(v.y), f2bf(v.z), f2bf(v.w));
    ((ushort4*)out)[i] = o;
  }
}

// ---------------- RoPE cos/sin table ----------------
__global__ void rope_table(float* __restrict__ cs, float* __restrict__ sn) {
  int idx = blockIdx.x * blockDim.x + threadIdx.x;   // S_LEN*64
  if (idx >= S_LEN * 64) return;
  int i = idx & 63, t = idx >> 6;
  float freq = powf(500000.0f, -(float)(2 * i) / 128.0f);
  float ang = (float)t * freq;
  cs[idx] = cosf(ang);
  sn[idx] = sinf(ang);
}

// ---------------- RoPE in-place on packed bf16 buffer ----------------
__global__ void rope_apply(u16* __restrict__ T, const float* __restrict__ cs,
                           const float* __restrict__ sn, int base, int nheads, int total) {
  int idx = blockIdx.x * blockDim.x + threadIdx.x;
  if (idx >= total) return;
  int i = idx & 63;
  int tmp = idx >> 6;
  int hh = tmp % nheads;
  int t  = tmp / nheads;
  u16* p = T + (size_t)t * QST + base + hh * HD + 2 * i;
  float c = cs[t * 64 + i], s = sn[t * 64 + i];
  float te = bf2f(p[0]), to = bf2f(p[1]);
  p[0] = f2bf(te * c - to * s);
  p[1] = f2bf(te * s + to * c);
}

// ======== 256 x (NB*64) 8-wave GEMM, BK=64, 2 phases/K-tile, counted vmcnt ====
// C[m,n] = sum_k A[m,k]*B[n,k]. 512 thr = 8 waves (wr 0..1, wc 0..3).
// Phase = A-half (qa). B frags cached across both phases of a tile.
// LDS/buffer: A = 2 x 16KB halves, B = NB x 8KB. Double-buffered.
// 16B-slot swizzle slot^=(row&7), both-sides (pre-swizzled source for linear
// global_load_lds dest; swizzled ds_read_b128) -> 0 bank conflicts (verified r3).
template<int NB, int OUT_BF16>
__device__ __forceinline__ void gemm256_body(const u16* __restrict__ A,
                                             const u16* __restrict__ Bm,
                                             void* __restrict__ Cout,
                                             int m0, int n0, int Nst, int Ks) {
  constexpr int BSZ  = NB * 4096;        // B u16 per buffer
  constexpr int SBUF = 16384 + BSZ;      // u16 per buffer
  __shared__ alignas(16) u16 lds[2 * SBUF];
  const int tid = threadIdx.x;
  const int w = tid >> 6, lane = tid & 63;
  const int lrow = lane & 15, lk = lane >> 4;
  const int wr = w >> 2, wc = w & 3;
  f32x4 acc[2][4][NB] = {};

  const int srow = tid >> 3;                 // staging row 0..63
  const int scol = (tid & 7) ^ (srow & 7);   // pre-swizzled source 16B slot
  const u16* Ag = A + (size_t)m0 * Ks;
  const u16* Bg = Bm + (size_t)n0 * Ks;

  const int sl0 = (lk ^ (lrow & 7)) * 8;     // kk=0 swizzled slot (u16)
  const int sl1 = ((4 + lk) ^ (lrow & 7)) * 8;
  const int aro = (wr * 64 + lrow) * 64;     // + mi*1024, within 128-row half
  const int bro = (wc * (NB * 16) + lrow) * 64;  // + ni*1024
  const int nkt = Ks >> 6;

#define STAGE_A(dst_u16, gbase) do { \
    const u16* _g = (gbase) + (size_t)srow * Ks + scol * 8; \
    async16(&lds[(dst_u16) + tid * 8], _g); \
    async16(&lds[(dst_u16) + tid * 8 + 4096], _g + (size_t)64 * Ks); \
  } while (0)
#define STAGE_B(dst_u16, gbase) do { \
    _Pragma("unroll") \
    for (int _j = 0; _j < NB; ++_j) { \
      int _idx = _j * 512 + tid; \
      int _br = _idx >> 3; \
      int _bs = (_idx & 7) ^ (_br & 7); \
      async16(&lds[(dst_u16) + _idx * 8], (gbase) + (size_t)_br * Ks + _bs * 8); \
    } \
  } while (0)
#define VM_P0 do { if constexpr (NB == 3) asm volatile("s_waitcnt vmcnt(5)" ::: "memory"); \
                   else                   asm volatile("s_waitcnt vmcnt(4)" ::: "memory"); } while (0)
#define VM_P1 asm volatile("s_waitcnt vmcnt(2)" ::: "memory")
#define VM_00 asm volatile("s_waitcnt vmcnt(0)" ::: "memory")
#define BARX  __builtin_amdgcn_s_barrier()

  // prologue tile 0, issue order: A0(2), B(NB), A1(2)
  STAGE_A(0,     Ag);
  STAGE_B(16384, Bg);
  STAGE_A(8192,  Ag + (size_t)128 * Ks);
  asm volatile("s_waitcnt vmcnt(2)" ::: "memory");   // A0 + B landed
  BARX;

  bf16x8 af[4][2], bf[NB][2];
  for (int t = 0; t < nkt; ++t) {
    const int cb = (t & 1) ? SBUF : 0;
    const int sb = (t & 1) ? 0 : SBUF;
    const u16* An = Ag + (t + 1) * 64;
    const u16* Bn = Bg + (t + 1) * 64;
    const bool st = (t + 1 < nkt);
    // ---- P0: qa=0; reads A0 + B; stages A0', B' ----
#pragma unroll
    for (int mi = 0; mi < 4; ++mi) {
      af[mi][0] = *(const bf16x8*)&lds[cb + aro + mi * 1024 + sl0];
      af[mi][1] = *(const bf16x8*)&lds[cb + aro + mi * 1024 + sl1];
    }
#pragma unroll
    for (int ni = 0; ni < NB; ++ni) {
      bf[ni][0] = *(const bf16x8*)&lds[cb + 16384 + bro + ni * 1024 + sl0];
      bf[ni][1] = *(const bf16x8*)&lds[cb + 16384 + bro + ni * 1024 + sl1];
    }
    if (st) { STAGE_A(sb, An); STAGE_B(sb + 16384, Bn); VM_P0; } else { VM_00; }
    BARX;
    __builtin_amdgcn_s_setprio(1);
#pragma unroll
    for (int mi = 0; mi < 4; ++mi)
#pragma unroll
      for (int ni = 0; ni < NB; ++ni) {
        acc[0][mi][ni] = MFMA16(af[mi][0], bf[ni][0], acc[0][mi][ni]);
        acc[0][mi][ni] = MFMA16(af[mi][1], bf[ni][1], acc[0][mi][ni]);
      }
    __builtin_amdgcn_s_setprio(0);
    BARX;
    // ---- P1: qa=1; reads A1 (B cached); stages A1' ----
#pragma unroll
    for (int mi = 0; mi < 4; ++mi) {
      af[mi][0] = *(const bf16x8*)&lds[cb + 8192 + aro + mi * 1024 + sl0];
      af[mi][1] = *(const bf16x8*)&lds[cb + 8192 + aro + mi * 1024 + sl1];
    }
    if (st) { STAGE_A(sb + 8192, An + (size_t)128 * Ks); VM_P1; }
    BARX;
    __builtin_amdgcn_s_setprio(1);
#pragma unroll
    for (int mi = 0; mi < 4; ++mi)
#pragma unroll
      for (int ni = 0; ni < NB; ++ni) {
        acc[1][mi][ni] = MFMA16(af[mi][0], bf[ni][0], acc[1][mi][ni]);
        acc[1][mi][ni] = MFMA16(af[mi][1], bf[ni][1], acc[1][mi][ni]);
      }
    __builtin_amdgcn_s_setprio(0);
    BARX;
  }
#undef STAGE_A
#undef STAGE_B
#undef VM_P0
#undef VM_P1
#undef VM_00
#undef BARX
  // ---- epilogue: C/D layout col=lane&15, row=(lane>>4)*4+j (m89-verified) ----
#pragma unroll
  for (int qa = 0; qa < 2; ++qa)
#pragma unroll
    for (int mi = 0; mi < 4; ++mi)
#pragma unroll
      for (int ni = 0; ni < NB; ++ni) {
        int row = m0 + qa * 128 + wr * 64 + mi * 16 + lk * 4;
        int col = n0 + wc * (NB * 16) + ni * 16 + lrow;
        if (OUT_BF16) {
          u16* C = (u16*)Cout;
#pragma unroll
          for (int j = 0; j < 4; ++j)
            C[(size_t)(row + j) * Nst + col] = f2bf(acc[qa][mi][ni][j]);
        } else {
          float* C = (float*)Cout;
#pragma unroll
          for (int j = 0; j < 4; ++j)
            C[(size_t)(row + j) * Nst + col] = acc[qa][mi][ni][j];
        }
      }
}

// QKV projection: x[2048][4096] @ wqkv[6144][4096]^T -> QKV[2048][6144].
// grid (32, 8) = 256 blocks = 1/CU. Bijective XCD swizzle: XCD c owns m-row c.
__global__ __launch_bounds__(512, 2) void gemm256_qkv(const u16* __restrict__ xb,
                                                      const u16* __restrict__ wqkvb,
                                                      u16* __restrict__ QKVb) {
  int lid = blockIdx.y * 32 + blockIdx.x;
  int swz = (lid & 7) * 32 + (lid >> 3);
  gemm256_body<3, 1>(xb, wqkvb, QKVb, (swz >> 5) * 256, (swz & 31) * 192, QST, 4096);
}

// output projection: AO[2048][4096] @ wo[4096][4096]^T -> out f32. grid (32, 8).
__global__ __launch_bounds__(512, 2) void gemm256_wo(const u16* __restrict__ AOb,
                                                     const u16* __restrict__ wob,
                                                     float* __restrict__ out) {
  int lid = blockIdx.y * 32 + blockIdx.x;
  int swz = (lid & 7) * 32 + (lid >> 3);
  gemm256_body<2, 0>(AOb, wob, out, (swz >> 5) * 256, (swz & 31) * 128, 4096, 4096);
}

// ---------------- flash attention: swapped-operand 32x32, causal, GQA ----
// Q/K/V read from the packed QKV buffer (row stride QST).
__global__ __launch_bounds__(256, 2) void attn_fwd2(const u16* __restrict__ QKVb,
                                                    u16* __restrict__ O) {
  __shared__ alignas(16) u16 Ks[64 * 128];    // [key][d], 256B rows, XOR-swizzled
  __shared__ alignas(16) u16 VTs[128 * 64];   // [d][kappa-pos], 128B rows, XOR-swizzled
  const u16* Km = QKVb + 4096;
  const u16* Vm = QKVb + 5120;
  const int tid = threadIdx.x;
  const int w = tid >> 6, lane = tid & 63;
  const int lq = lane & 31, hi = lane >> 5;
  const int bid = blockIdx.x;
  const int head = bid & 31;
  const int g = bid >> 5;
  const int qt = (g < 8) ? (15 - g) : (g - 8);   // long tiles dispatched first
  const int qt0 = qt * 128;
  const int hk = head >> 2;
  const float scale = 0.08838834764831845f;      // 1/sqrt(128)
  const int qw = qt0 + w * 32;
  const int qrow = qw + lq;

  // Q fragments (B-operand): col=q, chunk c covers d = c*16 + hi*8 + 0..7
  bf16x8 qf[8];
  {
    const u16* qp = QKVb + (size_t)qrow * QST + head * HD + hi * 8;
#pragma unroll
    for (int c = 0; c < 8; ++c)
      qf[c] = *(const bf16x8*)&qp[c * 16];
  }
  f32x16 o_acc[4] = {};
  float m_r = -3.0e38f, l_r = 0.f;

  const int NT = qt0 / 64 + 2;
  for (int t = 0; t < NT; ++t) {
    const int j0 = t * 64;
    // ---- stage K: 16KB via global_load_lds, source pre-swizzled ----
#pragma unroll
    for (int it = 0; it < 4; ++it) {
      int idx = it * 256 + tid;
      int row = idx >> 4, s16 = idx & 15;
      const char* src = (const char*)(Km + (size_t)(j0 + row) * QST + hk * HD)
                        + ((s16 * 16) ^ ((row & 7) << 4));
      async16((char*)Ks + idx * 16, src);
    }
    // ---- stage V transposed into kappa-order ----
    {
      int vr = lane;
      int pos = (vr & ~12) | ((vr & 4) << 1) | ((vr & 8) >> 1);
#pragma unroll
      for (int it = 0; it < 4; ++it) {
        int db = w * 32 + it * 8;
        const u16* vp = Vm + (size_t)(j0 + vr) * QST + hk * HD + db;
        uint4 raw = *(const uint4*)vp;
        const u16* pe = (const u16*)&raw;
#pragma unroll
        for (int e = 0; e < 8; ++e) {
          int d = db + e;
          *(u16*)((char*)VTs + d * 128 + ((pos * 2) ^ ((d & 7) << 4))) = pe[e];
        }
      }
    }
    __syncthreads();
    if (j0 <= qw + 31) {
      // ---- QK^T (swapped): s rows = keys, cols = q ----
      f32x16 s0 = {}, s1 = {};
      const int kswz = (lq & 7) << 4;
#pragma unroll
      for (int c = 0; c < 8; ++c) {
        int cbv = c * 32 + hi * 16;
        bf16x8 k0 = *(const bf16x8*)((const char*)Ks + lq * 256 + (cbv ^ kswz));
        bf16x8 k1 = *(const bf16x8*)((const char*)Ks + (32 + lq) * 256 + (cbv ^ kswz));
        s0 = __builtin_amdgcn_mfma_f32_32x32x16_bf16(k0, qf[c], s0, 0, 0, 0);
        s1 = __builtin_amdgcn_mfma_f32_32x32x16_bf16(k1, qf[c], s1, 0, 0, 0);
      }
      // ---- softmax (per-lane: lane owns column q) ----
      float p0[16], p1[16];
      float tm = -3.0e38f;
      const bool domask = (j0 + 63 > qw);
#pragma unroll
      for (int r = 0; r < 16; ++r) {
        int kk = (r & 3) + 8 * (r >> 2) + 4 * hi;
        float a = s0[r] * scale;
        float b = s1[r] * scale;
        if (domask) {
          if (j0 + kk > qrow)      a = -3.0e38f;
          if (j0 + 32 + kk > qrow) b = -3.0e38f;
        }
        p0[r] = a; p1[r] = b;
        tm = fmaxf(tm, fmaxf(a, b));
      }
      tm = fmaxf(tm, __shfl_xor(tm, 32));
      float mnew = fmaxf(m_r, tm);
      float corr = __expf(m_r - mnew);
      m_r = mnew;
      float rs = 0.f;
#pragma unroll
      for (int r = 0; r < 16; ++r) {
        p0[r] = __expf(p0[r] - mnew);
        p1[r] = __expf(p1[r] - mnew);
        rs += p0[r] + p1[r];
      }
      rs += __shfl_xor(rs, 32);
      l_r = l_r * corr + rs;
#pragma unroll
      for (int dt = 0; dt < 4; ++dt)
#pragma unroll
        for (int r = 0; r < 16; ++r) o_acc[dt][r] *= corr;
      // ---- pack P (own-lane kappa order) ----
      uint4 pk[4];
#pragma unroll
      for (int cc = 0; cc < 2; ++cc) {
        asm("v_cvt_pk_bf16_f32 %0, %1, %2" : "=v"(pk[cc].x)     : "v"(p0[8*cc+0]), "v"(p0[8*cc+1]));
        asm("v_cvt_pk_bf16_f32 %0, %1, %2" : "=v"(pk[cc].y)     : "v"(p0[8*cc+2]), "v"(p0[8*cc+3]));
        asm("v_cvt_pk_bf16_f32 %0, %1, %2" : "=v"(pk[cc].z)     : "v"(p0[8*cc+4]), "v"(p0[8*cc+5]));
        asm("v_cvt_pk_bf16_f32 %0, %1, %2" : "=v"(pk[cc].w)     : "v"(p0[8*cc+6]), "v"(p0[8*cc+7]));
        asm("v_cvt_pk_bf16_f32 %0, %1, %2" : "=v"(pk[2+cc].x)   : "v"(p1[8*cc+0]), "v"(p1[8*cc+1]));
        asm("v_cvt_pk_bf16_f32 %0, %1, %2" : "=v"(pk[2+cc].y)   : "v"(p1[8*cc+2]), "v"(p1[8*cc+3]));
        asm("v_cvt_pk_bf16_f32 %0, %1, %2" : "=v"(pk[2+cc].z)   : "v"(p1[8*cc+4]), "v"(p1[8*cc+5]));
        asm("v_cvt_pk_bf16_f32 %0, %1, %2" : "=v"(pk[2+cc].w)   : "v"(p1[8*cc+6]), "v"(p1[8*cc+7]));
      }
      // ---- PV: O[dt] += mfma(V^T-frag, P^T-frag) ----
#pragma unroll
      for (int dt = 0; dt < 4; ++dt) {
        const char* vrow = (const char*)VTs + (dt * 32 + lq) * 128;
#pragma unroll
        for (int c = 0; c < 4; ++c) {
          bf16x8 vf = *(const bf16x8*)(vrow + ((c * 32 + hi * 16) ^ kswz));
          bf16x8 pf = __builtin_bit_cast(bf16x8, pk[c]);
          o_acc[dt] = __builtin_amdgcn_mfma_f32_32x32x16_bf16(vf, pf, o_acc[dt], 0, 0, 0);
        }
      }
    }
    __syncthreads();
  }
  // ---- normalize + write (O stride = DIM) ----
  float inv = 1.0f / l_r;
  u16* op = O + (size_t)qrow * DIM + head * HD;
#pragma unroll
  for (int dt = 0; dt < 4; ++dt)
#pragma unroll
    for (int rq = 0; rq < 4; ++rq) {
      int d0 = dt * 32 + 8 * rq + 4 * hi;
      ushort4 o4;
      o4.x = f2bf(o_acc[dt][4 * rq + 0] * inv);
      o4.y = f2bf(o_acc[dt][4 * rq + 1] * inv);
      o4.z = f2bf(o_acc[dt][4 * rq + 2] * inv);
      o4.w = f2bf(o_acc[dt][4 * rq + 3] * inv);
      *(ushort4*)&op[d0] = o4;
    }
}

// ---------------- host launcher ----------------
extern "C" void kernel_launch(void* const* d_in, const int* in_sizes, int n_in,
                              void* d_out, int out_size, void* d_ws, size_t ws_size,
                              hipStream_t stream) {
  (void)in_sizes; (void)n_in; (void)out_size;
  const float* x  = (const float*)d_in[0];
  const float* wq = (const float*)d_in[2];
  const float* wk = (const float*)d_in[3];
  const float* wv = (const float*)d_in[4];
  const float* wo = (const float*)d_in[5];

  char* ws = (char*)d_ws;
  u16*   xb    = (u16*)(ws + 0);                      // 16 MB
  u16*   wqkvb = (u16*)(ws + 16777216ull);            // 48 MB [6144][4096]
  u16*   wob   = (u16*)(ws + 67108864ull);            // 32 MB
  u16*   QKVb  = (u16*)(ws + 100663296ull);           // 24 MB [2048][6144]
  u16*   AOb   = (u16*)(ws + 125829120ull);           // 16 MB [2048][4096]
  float* cosb  = (float*)(ws + 142606336ull);         // 512 KB
  float* sinb  = (float*)(ws + 143130624ull);         // 512 KB
  if (ws_size < 143654912ull) return;

  auto cg = [](int n4) { int g = (n4 + 255) / 256; return g > 2048 ? 2048 : g; };
  conv_bf16<<<cg(2097152), 256, 0, stream>>>(x,  xb, 2097152);
  conv_bf16<<<cg(4194304), 256, 0, stream>>>(wq, wqkvb,            4194304);
  conv_bf16<<<cg(1048576), 256, 0, stream>>>(wk, wqkvb + 16777216, 1048576);
  conv_bf16<<<cg(1048576), 256, 0, stream>>>(wv, wqkvb + 20971520, 1048576);
  conv_bf16<<<cg(4194304), 256, 0, stream>>>(wo, wob, 4194304);
  rope_table<<<512, 256, 0, stream>>>(cosb, sinb);

  gemm256_qkv<<<dim3(32, 8), 512, 0, stream>>>(xb, wqkvb, QKVb);

  rope_apply<<<16384, 256, 0, stream>>>(QKVb, cosb, sinb, 0,    NH,  4194304);
  rope_apply<<<4096,  256, 0, stream>>>(QKVb, cosb, sinb, 4096, NKV, 1048576);

  attn_fwd2<<<512, 256, 0, stream>>>(QKVb, AOb);

  gemm256_wo<<<dim3(32, 8), 512, 0, stream>>>(AOb, wob, (float*)d_out);
}